// Round 5
// baseline (588.962 us; speedup 1.0000x reference)
//
#include <hip/hip_runtime.h>
#include <cstdint>
#include <cstddef>

#define N_NODE 512
#define N_GRAPH 16
#define EMBED 768
#define NHEAD 12
#define HDIM 64
#define NB (N_GRAPH * NHEAD)      // 192 batches
#define MROWS (N_NODE * N_GRAPH)  // 8192 rows of the flattened x

typedef __attribute__((ext_vector_type(8))) __bf16 bf16x8;
typedef __attribute__((ext_vector_type(4))) float f32x4;
typedef __attribute__((ext_vector_type(4))) unsigned short u16x4;

__device__ inline unsigned short f2bf(float f) {
  unsigned u = __builtin_bit_cast(unsigned, f);
  u += 0x7fff + ((u >> 16) & 1);   // RNE
  return (unsigned short)(u >> 16);
}

__device__ inline void gload_lds16(const void* g, void* l) {
  __builtin_amdgcn_global_load_lds(
      (const __attribute__((address_space(1))) void*)g,
      (__attribute__((address_space(3))) void*)l, 16, 0, 0);
}

// ---------------- fp32 -> bf16 conversion (vectorized) ----------------
__global__ void cvt_kernel(const float* __restrict__ in,
                           unsigned short* __restrict__ out, int n4) {
  int i = blockIdx.x * blockDim.x + threadIdx.x;
  if (i >= n4) return;
  f32x4 v = reinterpret_cast<const f32x4*>(in)[i];
  u16x4 o;
  o.x = f2bf(v.x); o.y = f2bf(v.y); o.z = f2bf(v.z); o.w = f2bf(v.w);
  reinterpret_cast<u16x4*>(out)[i] = o;
}

// ---------------- fused QKV GEMM: C[m][n] = sum_k x[m][k]*W[n][k] ------
// 128x128 tile, BK=32, 4 waves (2x2 of 64x64), global_load_lds staging.
__global__ __launch_bounds__(256) void qkv_gemm(
    const unsigned short* __restrict__ xb,
    const unsigned short* __restrict__ wqb, const unsigned short* __restrict__ wkb,
    const unsigned short* __restrict__ wvb,
    const float* __restrict__ bq, const float* __restrict__ bk,
    const float* __restrict__ bv,
    unsigned short* __restrict__ qo, unsigned short* __restrict__ ko,
    unsigned short* __restrict__ vto) {
  __shared__ unsigned short As[128 * 32];
  __shared__ unsigned short Bs[128 * 32];
  const int z = blockIdx.z;
  const unsigned short* W = (z == 0) ? wqb : (z == 1) ? wkb : wvb;
  const float* bias = (z == 0) ? bq : (z == 1) ? bk : bv;
  const int m0 = blockIdx.x * 128, n0 = blockIdx.y * 128;
  const int tid = threadIdx.x;
  const int w = tid >> 6, lane = tid & 63, g = lane >> 4, c = lane & 15;
  const int wm = (w >> 1) * 64, wn = (w & 1) * 64;
  const int t1 = w * 128 + lane, t2 = t1 + 64;
  const unsigned short* a1 = xb + (size_t)(m0 + (t1 >> 2)) * EMBED + (t1 & 3) * 8;
  const unsigned short* a2 = xb + (size_t)(m0 + (t2 >> 2)) * EMBED + (t2 & 3) * 8;
  const unsigned short* b1 = W + (size_t)(n0 + (t1 >> 2)) * EMBED + (t1 & 3) * 8;
  const unsigned short* b2 = W + (size_t)(n0 + (t2 >> 2)) * EMBED + (t2 & 3) * 8;
  char* asb = (char*)As + w * 2048;
  char* bsb = (char*)Bs + w * 2048;
  f32x4 acc[4][4] = {};
  for (int k0 = 0; k0 < EMBED; k0 += 32) {
    gload_lds16(a1 + k0, asb);
    gload_lds16(a2 + k0, asb + 1024);
    gload_lds16(b1 + k0, bsb);
    gload_lds16(b2 + k0, bsb + 1024);
    __syncthreads();
    bf16x8 af[4], bfr[4];
#pragma unroll
    for (int mi = 0; mi < 4; ++mi)
      af[mi] = *reinterpret_cast<const bf16x8*>(&As[(wm + mi * 16 + c) * 32 + g * 8]);
#pragma unroll
    for (int ni = 0; ni < 4; ++ni)
      bfr[ni] = *reinterpret_cast<const bf16x8*>(&Bs[(wn + ni * 16 + c) * 32 + g * 8]);
#pragma unroll
    for (int mi = 0; mi < 4; ++mi)
#pragma unroll
      for (int ni = 0; ni < 4; ++ni)
        acc[mi][ni] = __builtin_amdgcn_mfma_f32_16x16x32_bf16(af[mi], bfr[ni],
                                                              acc[mi][ni], 0, 0, 0);
    __syncthreads();
  }
  // epilogue: scatter to attention-friendly layouts
#pragma unroll
  for (int mi = 0; mi < 4; ++mi) {
#pragma unroll
    for (int ni = 0; ni < 4; ++ni) {
#pragma unroll
      for (int i = 0; i < 4; ++i) {
        int m = m0 + wm + mi * 16 + g * 4 + i;   // C row = (lane>>4)*4 + reg
        int n = n0 + wn + ni * 16 + c;           // C col = lane&15
        float v = acc[mi][ni][i] + bias[n];
        int node = m >> 4, graph = m & 15, head = n >> 6, d = n & 63;
        size_t bidx = (size_t)(graph * NHEAD + head);
        if (z == 0) {
          v *= 0.125f;  // HEAD_DIM^-0.5
          qo[(bidx * N_NODE + node) * HDIM + d] = f2bf(v);
        } else if (z == 1) {
          ko[(bidx * N_NODE + node) * HDIM + d] = f2bf(v);
        } else {
          vto[(bidx * HDIM + d) * N_NODE + node] = f2bf(v);  // V transposed
        }
      }
    }
  }
}

// ---------------- flash attention over 512 keys ----------------
// grid (8 q-tiles, 192 b); 4 waves x 16 q-rows. K/V direct from global (L2).
__global__ __launch_bounds__(256) void attn_kernel(
    const unsigned short* __restrict__ qb, const unsigned short* __restrict__ kb,
    const unsigned short* __restrict__ vtb, const float* __restrict__ bias,
    const float* __restrict__ amask, const unsigned char* __restrict__ kpm,
    unsigned short* __restrict__ attn_out) {
  __shared__ unsigned short P[4][16 * 72];  // per-wave P transpose buffer
  const int b = blockIdx.y, qt = blockIdx.x;
  const int tid = threadIdx.x;
  const int w = tid >> 6, lane = tid & 63, g = lane >> 4, c = lane & 15;
  const int graph = b / NHEAD, head = b % NHEAD;
  const int qbase = qt * 64 + w * 16;
  const size_t bQ = (size_t)b * N_NODE;
  const unsigned short* qptr = qb + (bQ + qbase + c) * HDIM + g * 8;
  bf16x8 aq0 = *reinterpret_cast<const bf16x8*>(qptr);
  bf16x8 aq1 = *reinterpret_cast<const bf16x8*>(qptr + 32);
  f32x4 o[4] = {};
  float m_run[4], l_run[4];
#pragma unroll
  for (int i = 0; i < 4; ++i) { m_run[i] = -INFINITY; l_run[i] = 0.0f; }
  unsigned short* Pw = P[w];
  for (int it = 0; it < 8; ++it) {
    const int kbk = it * 64;
    f32x4 s[4];
#pragma unroll
    for (int kf = 0; kf < 4; ++kf) {
      const unsigned short* kp = kb + (bQ + kbk + kf * 16 + c) * HDIM + g * 8;
      bf16x8 b0 = *reinterpret_cast<const bf16x8*>(kp);
      bf16x8 b1 = *reinterpret_cast<const bf16x8*>(kp + 32);
      f32x4 acc = {};
      acc = __builtin_amdgcn_mfma_f32_16x16x32_bf16(aq0, b0, acc, 0, 0, 0);
      acc = __builtin_amdgcn_mfma_f32_16x16x32_bf16(aq1, b1, acc, 0, 0, 0);
      s[kf] = acc;
    }
    // add bias + mask, apply key padding
#pragma unroll
    for (int kf = 0; kf < 4; ++kf) {
      const int key = kbk + kf * 16 + c;
      const unsigned char pm = kpm[graph * N_NODE + key];
#pragma unroll
      for (int i = 0; i < 4; ++i) {
        const int q = qbase + g * 4 + i;
        float v;
        if (pm) {
          v = -1e30f;
        } else {
          v = s[kf][i] + bias[((size_t)b * N_NODE + q) * N_NODE + key] +
              amask[(size_t)q * N_NODE + key];
        }
        s[kf][i] = v;
      }
    }
    // online softmax: row max over 16 lanes (k within group) x 4 frags
    float mx[4];
#pragma unroll
    for (int i = 0; i < 4; ++i)
      mx[i] = fmaxf(fmaxf(s[0][i], s[1][i]), fmaxf(s[2][i], s[3][i]));
#pragma unroll
    for (int xm = 1; xm < 16; xm <<= 1)
#pragma unroll
      for (int i = 0; i < 4; ++i) mx[i] = fmaxf(mx[i], __shfl_xor(mx[i], xm, 64));
    float rs[4];
#pragma unroll
    for (int i = 0; i < 4; ++i) {
      float mn = fmaxf(m_run[i], mx[i]);
      float sc = __expf(m_run[i] - mn);
      m_run[i] = mn;
      l_run[i] *= sc;
      o[0][i] *= sc; o[1][i] *= sc; o[2][i] *= sc; o[3][i] *= sc;
      rs[i] = 0.0f;
    }
#pragma unroll
    for (int kf = 0; kf < 4; ++kf)
#pragma unroll
      for (int i = 0; i < 4; ++i) {
        float p = __expf(s[kf][i] - m_run[i]);
        rs[i] += p;
        Pw[(g * 4 + i) * 72 + kf * 16 + c] = f2bf(p);  // transpose via LDS
      }
#pragma unroll
    for (int xm = 1; xm < 16; xm <<= 1)
#pragma unroll
      for (int i = 0; i < 4; ++i) rs[i] += __shfl_xor(rs[i], xm, 64);
#pragma unroll
    for (int i = 0; i < 4; ++i) l_run[i] += rs[i];
    asm volatile("s_waitcnt lgkmcnt(0)" ::: "memory");  // wave-local LDS RAW
    // PV: O[q][d] += P[q][k] * V[k][d]  (V pre-transposed: vtb[b][d][node])
#pragma unroll
    for (int kc = 0; kc < 2; ++kc) {
      bf16x8 ap = *reinterpret_cast<const bf16x8*>(&Pw[c * 72 + kc * 32 + g * 8]);
#pragma unroll
      for (int dt = 0; dt < 4; ++dt) {
        const unsigned short* vp =
            vtb + ((size_t)b * HDIM + dt * 16 + c) * N_NODE + kbk + kc * 32 + g * 8;
        bf16x8 bv = *reinterpret_cast<const bf16x8*>(vp);
        o[dt] = __builtin_amdgcn_mfma_f32_16x16x32_bf16(ap, bv, o[dt], 0, 0, 0);
      }
    }
  }
  // epilogue: write attn (bf16) in [node][graph][head*64+d] layout for out-proj
#pragma unroll
  for (int i = 0; i < 4; ++i) {
    float inv = 1.0f / l_run[i];
    int node = qbase + g * 4 + i;
#pragma unroll
    for (int dt = 0; dt < 4; ++dt) {
      int d = dt * 16 + c;
      attn_out[((size_t)(node * N_GRAPH + graph)) * EMBED + head * HDIM + d] =
          f2bf(o[dt][i] * inv);
    }
  }
}

// ---------------- out projection GEMM -> fp32 out ----------------
__global__ __launch_bounds__(256) void oproj_gemm(
    const unsigned short* __restrict__ ab, const unsigned short* __restrict__ wob,
    const float* __restrict__ bo, float* __restrict__ out) {
  __shared__ unsigned short As[128 * 32];
  __shared__ unsigned short Bs[128 * 32];
  const int m0 = blockIdx.x * 128, n0 = blockIdx.y * 128;
  const int tid = threadIdx.x;
  const int w = tid >> 6, lane = tid & 63, g = lane >> 4, c = lane & 15;
  const int wm = (w >> 1) * 64, wn = (w & 1) * 64;
  const int t1 = w * 128 + lane, t2 = t1 + 64;
  const unsigned short* a1 = ab + (size_t)(m0 + (t1 >> 2)) * EMBED + (t1 & 3) * 8;
  const unsigned short* a2 = ab + (size_t)(m0 + (t2 >> 2)) * EMBED + (t2 & 3) * 8;
  const unsigned short* b1 = wob + (size_t)(n0 + (t1 >> 2)) * EMBED + (t1 & 3) * 8;
  const unsigned short* b2 = wob + (size_t)(n0 + (t2 >> 2)) * EMBED + (t2 & 3) * 8;
  char* asb = (char*)As + w * 2048;
  char* bsb = (char*)Bs + w * 2048;
  f32x4 acc[4][4] = {};
  for (int k0 = 0; k0 < EMBED; k0 += 32) {
    gload_lds16(a1 + k0, asb);
    gload_lds16(a2 + k0, asb + 1024);
    gload_lds16(b1 + k0, bsb);
    gload_lds16(b2 + k0, bsb + 1024);
    __syncthreads();
    bf16x8 af[4], bfr[4];
#pragma unroll
    for (int mi = 0; mi < 4; ++mi)
      af[mi] = *reinterpret_cast<const bf16x8*>(&As[(wm + mi * 16 + c) * 32 + g * 8]);
#pragma unroll
    for (int ni = 0; ni < 4; ++ni)
      bfr[ni] = *reinterpret_cast<const bf16x8*>(&Bs[(wn + ni * 16 + c) * 32 + g * 8]);
#pragma unroll
    for (int mi = 0; mi < 4; ++mi)
#pragma unroll
      for (int ni = 0; ni < 4; ++ni)
        acc[mi][ni] = __builtin_amdgcn_mfma_f32_16x16x32_bf16(af[mi], bfr[ni],
                                                              acc[mi][ni], 0, 0, 0);
    __syncthreads();
  }
#pragma unroll
  for (int mi = 0; mi < 4; ++mi) {
#pragma unroll
    for (int ni = 0; ni < 4; ++ni) {
#pragma unroll
      for (int i = 0; i < 4; ++i) {
        int m = m0 + wm + mi * 16 + g * 4 + i;
        int n = n0 + wn + ni * 16 + c;
        out[(size_t)m * EMBED + n] = acc[mi][ni][i] + bo[n];
      }
    }
  }
}

extern "C" void kernel_launch(void* const* d_in, const int* in_sizes, int n_in,
                              void* d_out, int out_size, void* d_ws, size_t ws_size,
                              hipStream_t stream) {
  const float* x = (const float*)d_in[0];
  const float* attn_bias = (const float*)d_in[1];
  const float* attn_mask = (const float*)d_in[2];
  const unsigned char* kpm = (const unsigned char*)d_in[3];
  const float* wq = (const float*)d_in[4];
  const float* bq = (const float*)d_in[5];
  const float* wk = (const float*)d_in[6];
  const float* bk = (const float*)d_in[7];
  const float* wv = (const float*)d_in[8];
  const float* bv = (const float*)d_in[9];
  const float* wo = (const float*)d_in[10];
  const float* bo = (const float*)d_in[11];

  char* ws = (char*)d_ws;
  const size_t xbf_b = (size_t)MROWS * EMBED * 2;       // 12.6 MB
  const size_t wbf_b = (size_t)EMBED * EMBED * 2;       // 1.18 MB
  const size_t qkv_b = (size_t)NB * N_NODE * HDIM * 2;  // 12.6 MB
  unsigned short* x_bf = (unsigned short*)ws;  ws += xbf_b;
  unsigned short* wq_bf = (unsigned short*)ws; ws += wbf_b;
  unsigned short* wk_bf = (unsigned short*)ws; ws += wbf_b;
  unsigned short* wv_bf = (unsigned short*)ws; ws += wbf_b;
  unsigned short* wo_bf = (unsigned short*)ws; ws += wbf_b;
  unsigned short* q_bf = (unsigned short*)ws;  ws += qkv_b;
  unsigned short* k_bf = (unsigned short*)ws;  ws += qkv_b;
  unsigned short* vt_bf = (unsigned short*)ws; ws += qkv_b;
  unsigned short* attn_bf = (unsigned short*)ws;

  const int n4x = MROWS * EMBED / 4;   // 1572864
  const int n4w = EMBED * EMBED / 4;   // 147456
  cvt_kernel<<<(n4x + 255) / 256, 256, 0, stream>>>(x, x_bf, n4x);
  cvt_kernel<<<(n4w + 255) / 256, 256, 0, stream>>>(wq, wq_bf, n4w);
  cvt_kernel<<<(n4w + 255) / 256, 256, 0, stream>>>(wk, wk_bf, n4w);
  cvt_kernel<<<(n4w + 255) / 256, 256, 0, stream>>>(wv, wv_bf, n4w);
  cvt_kernel<<<(n4w + 255) / 256, 256, 0, stream>>>(wo, wo_bf, n4w);

  qkv_gemm<<<dim3(MROWS / 128, EMBED / 128, 3), 256, 0, stream>>>(
      x_bf, wq_bf, wk_bf, wv_bf, bq, bk, bv, q_bf, k_bf, vt_bf);

  attn_kernel<<<dim3(N_NODE / 64, NB), 256, 0, stream>>>(
      q_bf, k_bf, vt_bf, attn_bias, attn_mask, kpm, attn_bf);

  oproj_gemm<<<dim3(MROWS / 128, EMBED / 128), 256, 0, stream>>>(
      attn_bf, wo_bf, bo, (float*)d_out);
}

// Round 7
// 536.118 us; speedup vs baseline: 1.0986x; 1.0986x over previous
//
#include <hip/hip_runtime.h>
#include <cstdint>
#include <cstddef>

#define N_NODE 512
#define N_GRAPH 16
#define EMBED 768
#define NHEAD 12
#define HDIM 64
#define NB (N_GRAPH * NHEAD)      // 192 batches
#define MROWS (N_NODE * N_GRAPH)  // 8192 rows of the flattened x

typedef __attribute__((ext_vector_type(8))) __bf16 bf16x8;
typedef __attribute__((ext_vector_type(4))) float f32x4;
typedef __attribute__((ext_vector_type(4))) unsigned short u16x4;

__device__ inline unsigned short f2bf(float f) {
  unsigned u = __builtin_bit_cast(unsigned, f);
  u += 0x7fff + ((u >> 16) & 1);   // RNE
  return (unsigned short)(u >> 16);
}

__device__ inline void gload_lds16(const void* g, void* l) {
  __builtin_amdgcn_global_load_lds(
      (const __attribute__((address_space(1))) void*)g,
      (__attribute__((address_space(3))) void*)l, 16, 0, 0);
}

// ---------------- fp32 -> bf16 conversion (vectorized) ----------------
__global__ void cvt_kernel(const float* __restrict__ in,
                           unsigned short* __restrict__ out, int n4) {
  int i = blockIdx.x * blockDim.x + threadIdx.x;
  if (i >= n4) return;
  f32x4 v = reinterpret_cast<const f32x4*>(in)[i];
  u16x4 o;
  o.x = f2bf(v.x); o.y = f2bf(v.y); o.z = f2bf(v.z); o.w = f2bf(v.w);
  reinterpret_cast<u16x4*>(out)[i] = o;
}

// ---------------- fused QKV GEMM: C[m][n] = sum_k x[m][k]*W[n][k] ------
// 128x128 tile, BK=32, 4 waves (2x2 of 64x64), global_load_lds staging.
__global__ __launch_bounds__(256) void qkv_gemm(
    const unsigned short* __restrict__ xb,
    const unsigned short* __restrict__ wqb, const unsigned short* __restrict__ wkb,
    const unsigned short* __restrict__ wvb,
    const float* __restrict__ bq, const float* __restrict__ bk,
    const float* __restrict__ bv,
    unsigned short* __restrict__ qo, unsigned short* __restrict__ ko,
    unsigned short* __restrict__ vto) {
  __shared__ unsigned short As[128 * 32];
  __shared__ unsigned short Bs[128 * 32];
  const int z = blockIdx.z;
  const unsigned short* W = (z == 0) ? wqb : (z == 1) ? wkb : wvb;
  const float* bias = (z == 0) ? bq : (z == 1) ? bk : bv;
  const int m0 = blockIdx.x * 128, n0 = blockIdx.y * 128;
  const int tid = threadIdx.x;
  const int w = tid >> 6, lane = tid & 63, g = lane >> 4, c = lane & 15;
  const int wm = (w >> 1) * 64, wn = (w & 1) * 64;
  const int t1 = w * 128 + lane, t2 = t1 + 64;
  const unsigned short* a1 = xb + (size_t)(m0 + (t1 >> 2)) * EMBED + (t1 & 3) * 8;
  const unsigned short* a2 = xb + (size_t)(m0 + (t2 >> 2)) * EMBED + (t2 & 3) * 8;
  const unsigned short* b1 = W + (size_t)(n0 + (t1 >> 2)) * EMBED + (t1 & 3) * 8;
  const unsigned short* b2 = W + (size_t)(n0 + (t2 >> 2)) * EMBED + (t2 & 3) * 8;
  char* asb = (char*)As + w * 2048;
  char* bsb = (char*)Bs + w * 2048;
  f32x4 acc[4][4] = {};
  for (int k0 = 0; k0 < EMBED; k0 += 32) {
    gload_lds16(a1 + k0, asb);
    gload_lds16(a2 + k0, asb + 1024);
    gload_lds16(b1 + k0, bsb);
    gload_lds16(b2 + k0, bsb + 1024);
    __syncthreads();
    bf16x8 af[4], bfr[4];
#pragma unroll
    for (int mi = 0; mi < 4; ++mi)
      af[mi] = *reinterpret_cast<const bf16x8*>(&As[(wm + mi * 16 + c) * 32 + g * 8]);
#pragma unroll
    for (int ni = 0; ni < 4; ++ni)
      bfr[ni] = *reinterpret_cast<const bf16x8*>(&Bs[(wn + ni * 16 + c) * 32 + g * 8]);
#pragma unroll
    for (int mi = 0; mi < 4; ++mi)
#pragma unroll
      for (int ni = 0; ni < 4; ++ni)
        acc[mi][ni] = __builtin_amdgcn_mfma_f32_16x16x32_bf16(af[mi], bfr[ni],
                                                              acc[mi][ni], 0, 0, 0);
    __syncthreads();
  }
  // epilogue: scatter to attention-friendly layouts
#pragma unroll
  for (int mi = 0; mi < 4; ++mi) {
#pragma unroll
    for (int ni = 0; ni < 4; ++ni) {
#pragma unroll
      for (int i = 0; i < 4; ++i) {
        int m = m0 + wm + mi * 16 + g * 4 + i;   // C row = (lane>>4)*4 + reg
        int n = n0 + wn + ni * 16 + c;           // C col = lane&15
        float v = acc[mi][ni][i] + bias[n];
        int node = m >> 4, graph = m & 15, head = n >> 6, d = n & 63;
        size_t bidx = (size_t)(graph * NHEAD + head);
        if (z == 0) {
          v *= 0.125f;  // HEAD_DIM^-0.5
          qo[(bidx * N_NODE + node) * HDIM + d] = f2bf(v);
        } else if (z == 1) {
          ko[(bidx * N_NODE + node) * HDIM + d] = f2bf(v);
        } else {
          vto[(bidx * HDIM + d) * N_NODE + node] = f2bf(v);  // V transposed
        }
      }
    }
  }
}

// ---------------- flash attention over 512 keys (swapped QK^T) ----------
// Score layout: q = lane&15, key = (lane>>4)*4 + reg  -> float4 bias loads.
__global__ __launch_bounds__(256) void attn_kernel(
    const unsigned short* __restrict__ qb, const unsigned short* __restrict__ kb,
    const unsigned short* __restrict__ vtb, const float* __restrict__ bias,
    const float* __restrict__ amask, const unsigned char* __restrict__ kpm,
    unsigned short* __restrict__ attn_out) {
  __shared__ unsigned short P[4][16 * 72];  // per-wave P buffer [q][key]
  const int b = blockIdx.y, qt = blockIdx.x;
  const int tid = threadIdx.x;
  const int w = tid >> 6, lane = tid & 63, g = lane >> 4, c = lane & 15;
  const int graph = b / NHEAD, head = b % NHEAD;
  const int qbase = qt * 64 + w * 16;
  const size_t bQ = (size_t)b * N_NODE;
  const unsigned short* qptr = qb + (bQ + qbase + c) * HDIM + g * 8;
  bf16x8 aq0 = *reinterpret_cast<const bf16x8*>(qptr);
  bf16x8 aq1 = *reinterpret_cast<const bf16x8*>(qptr + 32);
  f32x4 o[4] = {};
  float m_run = -INFINITY, l_run = 0.0f;  // per q = c (scalar per lane)
  const float* bias_row = bias + ((size_t)b * N_NODE + qbase + c) * N_NODE;
  const float* amask_row = amask + (size_t)(qbase + c) * N_NODE;
  const unsigned char* kpm_row = kpm + graph * N_NODE;
  unsigned short* Pw = P[w];
  for (int it = 0; it < 8; ++it) {
    const int kbk = it * 64;
    f32x4 s[4];
#pragma unroll
    for (int kf = 0; kf < 4; ++kf) {
      const unsigned short* kp = kb + (bQ + kbk + kf * 16 + c) * HDIM + g * 8;
      bf16x8 b0 = *reinterpret_cast<const bf16x8*>(kp);
      bf16x8 b1 = *reinterpret_cast<const bf16x8*>(kp + 32);
      f32x4 acc = {};
      acc = __builtin_amdgcn_mfma_f32_16x16x32_bf16(b0, aq0, acc, 0, 0, 0);  // swapped
      acc = __builtin_amdgcn_mfma_f32_16x16x32_bf16(b1, aq1, acc, 0, 0, 0);
      s[kf] = acc;
    }
    // bias + mask + padding: reg i = key kbk+kf*16+g*4+i, q = qbase+c
#pragma unroll
    for (int kf = 0; kf < 4; ++kf) {
      const int k4 = kbk + kf * 16 + g * 4;
      f32x4 bv4 = *reinterpret_cast<const f32x4*>(bias_row + k4);
      f32x4 mv4 = *reinterpret_cast<const f32x4*>(amask_row + k4);
      unsigned pm4 = *reinterpret_cast<const unsigned*>(kpm_row + k4);
#pragma unroll
      for (int i = 0; i < 4; ++i) {
        float v = s[kf][i] + bv4[i] + mv4[i];
        s[kf][i] = ((pm4 >> (8 * i)) & 0xffu) ? -1e30f : v;
      }
    }
    // row max: 16 in-lane values, then 2-step butterfly across g-groups
    float mx = s[0][0];
#pragma unroll
    for (int kf = 0; kf < 4; ++kf)
#pragma unroll
      for (int i = 0; i < 4; ++i) mx = fmaxf(mx, s[kf][i]);
    mx = fmaxf(mx, __shfl_xor(mx, 16, 64));
    mx = fmaxf(mx, __shfl_xor(mx, 32, 64));
    const float mn = fmaxf(m_run, mx);
    const float sc = __expf(m_run - mn);
    m_run = mn;
    // P = exp(s - m), row sum, vectorized LDS write
    float rs = 0.0f;
#pragma unroll
    for (int kf = 0; kf < 4; ++kf) {
      u16x4 pw;
#pragma unroll
      for (int i = 0; i < 4; ++i) {
        float p = __expf(s[kf][i] - mn);
        rs += p;
        pw[i] = f2bf(p);
      }
      *reinterpret_cast<u16x4*>(&Pw[c * 72 + kf * 16 + g * 4]) = pw;
    }
    rs += __shfl_xor(rs, 16, 64);
    rs += __shfl_xor(rs, 32, 64);
    l_run = l_run * sc + rs;
    // rescale o: o-layout has q = g*4+i; sc for that q is held by lane (g*4+i)
    float scq[4];
#pragma unroll
    for (int i = 0; i < 4; ++i) scq[i] = __shfl(sc, (lane >> 4) * 4 + i, 64);
#pragma unroll
    for (int dt = 0; dt < 4; ++dt)
#pragma unroll
      for (int i = 0; i < 4; ++i) o[dt][i] *= scq[i];
    asm volatile("s_waitcnt lgkmcnt(0)" ::: "memory");  // wave-local LDS RAW
    // PV: O[q][d] += P[q][k] * V[k][d]  (V pre-transposed: vtb[b][d][node])
#pragma unroll
    for (int kc = 0; kc < 2; ++kc) {
      bf16x8 ap = *reinterpret_cast<const bf16x8*>(&Pw[c * 72 + kc * 32 + g * 8]);
#pragma unroll
      for (int dt = 0; dt < 4; ++dt) {
        const unsigned short* vp =
            vtb + ((size_t)b * HDIM + dt * 16 + c) * N_NODE + kbk + kc * 32 + g * 8;
        bf16x8 bv = *reinterpret_cast<const bf16x8*>(vp);
        o[dt] = __builtin_amdgcn_mfma_f32_16x16x32_bf16(ap, bv, o[dt], 0, 0, 0);
      }
    }
  }
  // epilogue: l for q=g*4+i lives in lane (g*4+i); redistribute, write out
  float invq[4];
#pragma unroll
  for (int i = 0; i < 4; ++i)
    invq[i] = 1.0f / __shfl(l_run, (lane >> 4) * 4 + i, 64);
#pragma unroll
  for (int i = 0; i < 4; ++i) {
    int node = qbase + g * 4 + i;
#pragma unroll
    for (int dt = 0; dt < 4; ++dt) {
      int d = dt * 16 + c;
      attn_out[((size_t)(node * N_GRAPH + graph)) * EMBED + head * HDIM + d] =
          f2bf(o[dt][i] * invq[i]);
    }
  }
}

// ---------------- out projection GEMM -> fp32 out ----------------
__global__ __launch_bounds__(256) void oproj_gemm(
    const unsigned short* __restrict__ ab, const unsigned short* __restrict__ wob,
    const float* __restrict__ bo, float* __restrict__ out) {
  __shared__ unsigned short As[128 * 32];
  __shared__ unsigned short Bs[128 * 32];
  const int m0 = blockIdx.x * 128, n0 = blockIdx.y * 128;
  const int tid = threadIdx.x;
  const int w = tid >> 6, lane = tid & 63, g = lane >> 4, c = lane & 15;
  const int wm = (w >> 1) * 64, wn = (w & 1) * 64;
  const int t1 = w * 128 + lane, t2 = t1 + 64;
  const unsigned short* a1 = ab + (size_t)(m0 + (t1 >> 2)) * EMBED + (t1 & 3) * 8;
  const unsigned short* a2 = ab + (size_t)(m0 + (t2 >> 2)) * EMBED + (t2 & 3) * 8;
  const unsigned short* b1 = wob + (size_t)(n0 + (t1 >> 2)) * EMBED + (t1 & 3) * 8;
  const unsigned short* b2 = wob + (size_t)(n0 + (t2 >> 2)) * EMBED + (t2 & 3) * 8;
  char* asb = (char*)As + w * 2048;
  char* bsb = (char*)Bs + w * 2048;
  f32x4 acc[4][4] = {};
  for (int k0 = 0; k0 < EMBED; k0 += 32) {
    gload_lds16(a1 + k0, asb);
    gload_lds16(a2 + k0, asb + 1024);
    gload_lds16(b1 + k0, bsb);
    gload_lds16(b2 + k0, bsb + 1024);
    __syncthreads();
    bf16x8 af[4], bfr[4];
#pragma unroll
    for (int mi = 0; mi < 4; ++mi)
      af[mi] = *reinterpret_cast<const bf16x8*>(&As[(wm + mi * 16 + c) * 32 + g * 8]);
#pragma unroll
    for (int ni = 0; ni < 4; ++ni)
      bfr[ni] = *reinterpret_cast<const bf16x8*>(&Bs[(wn + ni * 16 + c) * 32 + g * 8]);
#pragma unroll
    for (int mi = 0; mi < 4; ++mi)
#pragma unroll
      for (int ni = 0; ni < 4; ++ni)
        acc[mi][ni] = __builtin_amdgcn_mfma_f32_16x16x32_bf16(af[mi], bfr[ni],
                                                              acc[mi][ni], 0, 0, 0);
    __syncthreads();
  }
#pragma unroll
  for (int mi = 0; mi < 4; ++mi) {
#pragma unroll
    for (int ni = 0; ni < 4; ++ni) {
#pragma unroll
      for (int i = 0; i < 4; ++i) {
        int m = m0 + wm + mi * 16 + g * 4 + i;
        int n = n0 + wn + ni * 16 + c;
        out[(size_t)m * EMBED + n] = acc[mi][ni][i] + bo[n];
      }
    }
  }
}

extern "C" void kernel_launch(void* const* d_in, const int* in_sizes, int n_in,
                              void* d_out, int out_size, void* d_ws, size_t ws_size,
                              hipStream_t stream) {
  const float* x = (const float*)d_in[0];
  const float* attn_bias = (const float*)d_in[1];
  const float* attn_mask = (const float*)d_in[2];
  const unsigned char* kpm = (const unsigned char*)d_in[3];
  const float* wq = (const float*)d_in[4];
  const float* bq = (const float*)d_in[5];
  const float* wk = (const float*)d_in[6];
  const float* bk = (const float*)d_in[7];
  const float* wv = (const float*)d_in[8];
  const float* bv = (const float*)d_in[9];
  const float* wo = (const float*)d_in[10];
  const float* bo = (const float*)d_in[11];

  char* ws = (char*)d_ws;
  const size_t xbf_b = (size_t)MROWS * EMBED * 2;       // 12.6 MB
  const size_t wbf_b = (size_t)EMBED * EMBED * 2;       // 1.18 MB
  const size_t qkv_b = (size_t)NB * N_NODE * HDIM * 2;  // 12.6 MB
  unsigned short* x_bf = (unsigned short*)ws;  ws += xbf_b;
  unsigned short* wq_bf = (unsigned short*)ws; ws += wbf_b;
  unsigned short* wk_bf = (unsigned short*)ws; ws += wbf_b;
  unsigned short* wv_bf = (unsigned short*)ws; ws += wbf_b;
  unsigned short* wo_bf = (unsigned short*)ws; ws += wbf_b;
  unsigned short* q_bf = (unsigned short*)ws;  ws += qkv_b;
  unsigned short* k_bf = (unsigned short*)ws;  ws += qkv_b;
  unsigned short* vt_bf = (unsigned short*)ws; ws += qkv_b;
  unsigned short* attn_bf = (unsigned short*)ws;

  const int n4x = MROWS * EMBED / 4;   // 1572864
  const int n4w = EMBED * EMBED / 4;   // 147456
  cvt_kernel<<<(n4x + 255) / 256, 256, 0, stream>>>(x, x_bf, n4x);
  cvt_kernel<<<(n4w + 255) / 256, 256, 0, stream>>>(wq, wq_bf, n4w);
  cvt_kernel<<<(n4w + 255) / 256, 256, 0, stream>>>(wk, wk_bf, n4w);
  cvt_kernel<<<(n4w + 255) / 256, 256, 0, stream>>>(wv, wv_bf, n4w);
  cvt_kernel<<<(n4w + 255) / 256, 256, 0, stream>>>(wo, wo_bf, n4w);

  qkv_gemm<<<dim3(MROWS / 128, EMBED / 128, 3), 256, 0, stream>>>(
      x_bf, wq_bf, wk_bf, wv_bf, bq, bk, bv, q_bf, k_bf, vt_bf);

  attn_kernel<<<dim3(N_NODE / 64, NB), 256, 0, stream>>>(
      q_bf, k_bf, vt_bf, attn_bias, attn_mask, kpm, attn_bf);

  oproj_gemm<<<dim3(MROWS / 128, EMBED / 128), 256, 0, stream>>>(
      attn_bf, wo_bf, bo, (float*)d_out);
}